// Round 1
// baseline (6000.242 us; speedup 1.0000x reference)
//
#include <hip/hip_runtime.h>
#include <math.h>

#define DIMC 384
#define NB   256
#define EPSV 1e-5f

// ---------------------------------------------------------------------------
// Kernel 1: bbox clip-feature gather.  target (B,576,384) -> ta (B,384,144)
// channel-major, via LDS transpose (both global sides coalesced).
// ---------------------------------------------------------------------------
__global__ __launch_bounds__(256) void gather_kernel(
    const float* __restrict__ target,
    const float* __restrict__ bbox,
    float* __restrict__ ta)
{
    const int b = blockIdx.x;
    const int t = threadIdx.x;

    __shared__ int pos[144];
    __shared__ float ls[64 * 145];   // 64 channels x 144 pixels, stride 145 (odd)

    // bbox math (redundant per-thread, trivial cost)
    const float bx0 = bbox[b * 4 + 0] * 24.f;
    const float by0 = bbox[b * 4 + 1] * 24.f;
    const float bw  = bbox[b * 4 + 2] * 24.f;
    const float bh  = bbox[b * 4 + 3] * 24.f;
    const float l0 = (bw + bh) * 0.5f;
    const float l  = sqrtf((bw + l0) * (bh + l0));
    const int xmin = (int)fminf(fmaxf(ceilf (bx0 - l * 0.5f), 0.f), 23.f);
    const int ymin = (int)fminf(fmaxf(ceilf (by0 - l * 0.5f), 0.f), 23.f);
    const int xmax = (int)fminf(fmaxf(truncf(bx0 + l * 0.5f), 0.f), 23.f);
    const int ymax = (int)fminf(fmaxf(truncf(by0 + l * 0.5f), 0.f), 23.f);

    if (t < 144) {
        const int i = t / 12, j = t % 12;
        int r = ymin + (i * (ymax - ymin)) / 12;   // non-negative -> floor div
        int c = xmin + (j * (xmax - xmin)) / 12;
        r = min(max(r, 0), 23);
        c = min(max(c, 0), 23);
        pos[t] = r * 24 + c;
    }
    __syncthreads();

    const float* tb  = target + (size_t)b * 576 * 384;
    float*       tab = ta     + (size_t)b * 384 * 144;

    const int sub = t >> 6;    // 0..3 (pixel sub-slot)
    const int cc  = t & 63;    // channel within tile

    for (int ct = 0; ct < 6; ++ct) {
        // load: coalesced over channels, scatter into LDS (odd stride: no conflicts)
        for (int p0 = 0; p0 < 144; p0 += 4) {
            const int p = p0 + sub;
            ls[cc * 145 + p] = tb[(size_t)pos[p] * 384 + ct * 64 + cc];
        }
        __syncthreads();
        // store: coalesced over pixels
        for (int idx = t; idx < 64 * 144; idx += 256) {
            const int c2 = idx / 144;
            const int p  = idx - c2 * 144;
            tab[(size_t)(ct * 64 + c2) * 144 + p] = ls[c2 * 145 + p];
        }
        __syncthreads();
    }
}

// ---------------------------------------------------------------------------
// Kernel 2: 5x5 conv (replicate pad 2) + BN + leaky -> h1 (B,384,144)
// block = (oc tile of 32, batch).  Thread owns a 3x6 output block.
// Lanes are oc-fastest: LDS input reads broadcast, weight reads stride-25.
// ---------------------------------------------------------------------------
__global__ __launch_bounds__(256) void conv1_kernel(
    const float* __restrict__ ta,
    const float* __restrict__ W1,
    const float* __restrict__ g1, const float* __restrict__ b1,
    const float* __restrict__ m1, const float* __restrict__ v1,
    float* __restrict__ h1)
{
    const int b   = blockIdx.y;
    const int oc0 = blockIdx.x * 32;
    const int t   = threadIdx.x;
    const int ocl = t & 31;
    const int pg  = t >> 5;          // 0..7
    const int by  = pg >> 1;         // 0..3
    const int bx  = pg & 1;          // 0..1

    __shared__ __attribute__((aligned(16))) float in_pad[16 * 16];  // rows/cols -2..13
    __shared__ float w_s[32 * 25];
    __shared__ float lds_out[32 * 145];

    float acc[3][6];
#pragma unroll
    for (int i = 0; i < 3; ++i)
#pragma unroll
        for (int j = 0; j < 6; ++j) acc[i][j] = 0.f;

    const float* tab = ta + (size_t)b * 384 * 144;
    const float* Wg  = W1 + (size_t)oc0 * 384 * 25;

    for (int ic = 0; ic < 384; ++ic) {
        {   // stage padded input tile (16x16)
            const int r = t >> 4, c = t & 15;
            const int rr = min(max(r - 2, 0), 11);
            const int c2 = min(max(c - 2, 0), 11);
            in_pad[t] = tab[ic * 144 + rr * 12 + c2];
        }
        for (int idx = t; idx < 32 * 25; idx += 256) {   // stage weights
            const int o = idx / 25, tap = idx - o * 25;
            w_s[idx] = Wg[(size_t)o * 384 * 25 + ic * 25 + tap];
        }
        __syncthreads();

#pragma unroll
        for (int ky = 0; ky < 5; ++ky) {
            float row[3][12];
#pragma unroll
            for (int dy = 0; dy < 3; ++dy) {
                const int ir = by * 3 + dy + ky;          // 0..13
                const float* rp = &in_pad[ir * 16 + bx * 6];
#pragma unroll
                for (int i = 0; i < 12; i += 2) {
                    const float2 v2 = *(const float2*)&rp[i];
                    row[dy][i] = v2.x; row[dy][i + 1] = v2.y;
                }
            }
#pragma unroll
            for (int kx = 0; kx < 5; ++kx) {
                const float wv = w_s[ocl * 25 + ky * 5 + kx];
#pragma unroll
                for (int dy = 0; dy < 3; ++dy)
#pragma unroll
                    for (int dx = 0; dx < 6; ++dx)
                        acc[dy][dx] = fmaf(wv, row[dy][kx + dx], acc[dy][dx]);
            }
        }
        __syncthreads();
    }

    // BN + leaky, transpose through LDS so global stores are coalesced
    const int oc = oc0 + ocl;
    const float scale = g1[oc] * rsqrtf(v1[oc] + EPSV);
    const float shift = b1[oc] - m1[oc] * scale;
#pragma unroll
    for (int dy = 0; dy < 3; ++dy)
#pragma unroll
        for (int dx = 0; dx < 6; ++dx) {
            float v = acc[dy][dx] * scale + shift;
            v = (v >= 0.f) ? v : 0.01f * v;
            const int p = (by * 3 + dy) * 12 + bx * 6 + dx;
            lds_out[ocl * 145 + p] = v;
        }
    __syncthreads();
    float* h1b = h1 + (size_t)b * 384 * 144 + (size_t)oc0 * 144;
    for (int idx = t; idx < 32 * 144; idx += 256) {
        const int o = idx / 144;
        const int p = idx - o * 144;
        h1b[o * 144 + p] = lds_out[o * 145 + p];
    }
}

// ---------------------------------------------------------------------------
// Kernel 3: 3x3 conv (replicate pad 1) + BN + leaky + residual add + transpose
// out (B,144,384).  Lanes oc-fastest -> fully coalesced 128B out stores.
// ---------------------------------------------------------------------------
__global__ __launch_bounds__(256) void conv2_kernel(
    const float* __restrict__ h1,
    const float* __restrict__ temp,
    const float* __restrict__ W2,
    const float* __restrict__ g2, const float* __restrict__ b2,
    const float* __restrict__ m2, const float* __restrict__ v2,
    float* __restrict__ out)
{
    const int b   = blockIdx.y;
    const int oc0 = blockIdx.x * 32;
    const int t   = threadIdx.x;
    const int ocl = t & 31;
    const int pg  = t >> 5;
    const int by  = pg >> 1;
    const int bx  = pg & 1;

    __shared__ __attribute__((aligned(16))) float in_pad[14 * 16];  // rows/cols -1..12
    __shared__ float w_s[32 * 9];

    float acc[3][6];
#pragma unroll
    for (int i = 0; i < 3; ++i)
#pragma unroll
        for (int j = 0; j < 6; ++j) acc[i][j] = 0.f;

    const float* h1b = h1 + (size_t)b * 384 * 144;
    const float* Wg  = W2 + (size_t)oc0 * 384 * 9;

    for (int ic = 0; ic < 384; ++ic) {
        if (t < 14 * 16) {   // stage padded input tile (14 rows x 16 cols; cols 14..15 unused)
            const int r = t >> 4, c = t & 15;
            const int rr = min(max(r - 1, 0), 11);
            const int c2 = min(max(c - 1, 0), 11);
            in_pad[t] = h1b[ic * 144 + rr * 12 + c2];
        }
        for (int idx = t; idx < 32 * 9; idx += 256) {
            const int o = idx / 9, tap = idx - o * 9;
            w_s[idx] = Wg[(size_t)o * 384 * 9 + ic * 9 + tap];
        }
        __syncthreads();

#pragma unroll
        for (int ky = 0; ky < 3; ++ky) {
            float row[3][8];
#pragma unroll
            for (int dy = 0; dy < 3; ++dy) {
                const int ir = by * 3 + dy + ky;          // 0..13
                const float* rp = &in_pad[ir * 16 + bx * 6];
#pragma unroll
                for (int i = 0; i < 8; i += 2) {
                    const float2 v2 = *(const float2*)&rp[i];
                    row[dy][i] = v2.x; row[dy][i + 1] = v2.y;
                }
            }
#pragma unroll
            for (int kx = 0; kx < 3; ++kx) {
                const float wv = w_s[ocl * 9 + ky * 3 + kx];
#pragma unroll
                for (int dy = 0; dy < 3; ++dy)
#pragma unroll
                    for (int dx = 0; dx < 6; ++dx)
                        acc[dy][dx] = fmaf(wv, row[dy][kx + dx], acc[dy][dx]);
            }
        }
        __syncthreads();
    }

    // BN + leaky + residual, direct coalesced store to out[b][p][c]
    const int oc = oc0 + ocl;
    const float scale = g2[oc] * rsqrtf(v2[oc] + EPSV);
    const float shift = b2[oc] - m2[oc] * scale;
    const float* tpb = temp + (size_t)b * 144 * 384;
    float*       ob  = out  + (size_t)b * 144 * 384;
#pragma unroll
    for (int dy = 0; dy < 3; ++dy)
#pragma unroll
        for (int dx = 0; dx < 6; ++dx) {
            float v = acc[dy][dx] * scale + shift;
            v = (v >= 0.f) ? v : 0.01f * v;
            const int p = (by * 3 + dy) * 12 + bx * 6 + dx;
            ob[(size_t)p * 384 + oc] = tpb[(size_t)p * 384 + oc] + v;
        }
}

// ---------------------------------------------------------------------------
extern "C" void kernel_launch(void* const* d_in, const int* in_sizes, int n_in,
                              void* d_out, int out_size, void* d_ws, size_t ws_size,
                              hipStream_t stream) {
    const float* temp   = (const float*)d_in[0];
    const float* target = (const float*)d_in[1];
    const float* bbox   = (const float*)d_in[2];
    const float* W1     = (const float*)d_in[3];
    const float* g1     = (const float*)d_in[4];
    const float* b1     = (const float*)d_in[5];
    const float* m1     = (const float*)d_in[6];
    const float* v1     = (const float*)d_in[7];
    const float* W2     = (const float*)d_in[8];
    const float* g2     = (const float*)d_in[9];
    const float* b2     = (const float*)d_in[10];
    const float* m2     = (const float*)d_in[11];
    const float* v2     = (const float*)d_in[12];
    float* out = (float*)d_out;

    float* ta = (float*)d_ws;                                   // (256,384,144)
    float* h1 = ta + (size_t)NB * DIMC * 144;                   // (256,384,144)

    gather_kernel<<<dim3(NB), dim3(256), 0, stream>>>(target, bbox, ta);
    conv1_kernel<<<dim3(12, NB), dim3(256), 0, stream>>>(ta, W1, g1, b1, m1, v1, h1);
    conv2_kernel<<<dim3(12, NB), dim3(256), 0, stream>>>(h1, temp, W2, g2, b2, m2, v2, out);
}

// Round 2
// 986.867 us; speedup vs baseline: 6.0801x; 6.0801x over previous
//
#include <hip/hip_runtime.h>
#include <math.h>

#define NBATCH 256
#define CDIM   384

typedef __attribute__((ext_vector_type(4))) float  f32x4;
typedef __attribute__((ext_vector_type(8))) __bf16 bf16x8;

__device__ __forceinline__ void load16(const void* g, void* l) {
    __builtin_amdgcn_global_load_lds(
        (const __attribute__((address_space(1))) void*)g,
        (__attribute__((address_space(3))) void*)l, 16, 0, 0);
}

// ---------------------------------------------------------------------------
// Gather: target (B,576,384) fp32 -> ta (B,144,384) bf16, pixel-major.
// ---------------------------------------------------------------------------
__global__ __launch_bounds__(256) void gather_bf16(
    const float* __restrict__ target,
    const float* __restrict__ bbox,
    __bf16* __restrict__ ta)
{
    const int b = blockIdx.x, t = threadIdx.x;
    __shared__ int pos[144];

    if (t < 144) {
        const float bx0 = bbox[b * 4 + 0] * 24.f;
        const float by0 = bbox[b * 4 + 1] * 24.f;
        const float bw  = bbox[b * 4 + 2] * 24.f;
        const float bh  = bbox[b * 4 + 3] * 24.f;
        const float l0 = (bw + bh) * 0.5f;
        const float l  = sqrtf((bw + l0) * (bh + l0));
        const int xmin = (int)fminf(fmaxf(ceilf (bx0 - l * 0.5f), 0.f), 23.f);
        const int ymin = (int)fminf(fmaxf(ceilf (by0 - l * 0.5f), 0.f), 23.f);
        const int xmax = (int)fminf(fmaxf(truncf(bx0 + l * 0.5f), 0.f), 23.f);
        const int ymax = (int)fminf(fmaxf(truncf(by0 + l * 0.5f), 0.f), 23.f);
        const int i = t / 12, j = t % 12;
        int r = ymin + (i * (ymax - ymin)) / 12;
        int c = xmin + (j * (xmax - xmin)) / 12;
        r = min(max(r, 0), 23);
        c = min(max(c, 0), 23);
        pos[t] = r * 24 + c;
    }
    __syncthreads();

    const float* tb  = target + (size_t)b * 576 * 384;
    __bf16*      tab = ta     + (size_t)b * 144 * 384;
    for (int idx = t; idx < 144 * 384; idx += 256) {
        const int p = idx / 384, c = idx - p * 384;
        tab[idx] = (__bf16)tb[(size_t)pos[p] * 384 + c];
    }
}

// ---------------------------------------------------------------------------
// Weight prep: W (oc, ic, taps) fp32 -> Wt (oc, tap, ic) bf16
// ---------------------------------------------------------------------------
__global__ __launch_bounds__(256) void prep_w(
    const float* __restrict__ W, __bf16* __restrict__ Wt, int taps)
{
    const int idx = blockIdx.x * 256 + threadIdx.x;
    const int total = 384 * 384 * taps;
    if (idx >= total) return;
    const int oc  = idx / (384 * taps);
    const int rem = idx - oc * 384 * taps;
    const int tap = rem / 384;
    const int ic  = rem - tap * 384;
    Wt[idx] = (__bf16)W[((size_t)oc * 384 + ic) * taps + tap];
}

// ---------------------------------------------------------------------------
// Implicit-GEMM conv (tap-decomposed) + BN + leaky (+ residual).
// A: (B*144, 384) bf16 pixel-major image.  Wt: (384, TAPS*384) bf16.
// Block: BM=128 x BN=128, 4 waves, each wave 64x64 via 4x4 mfma 16x16x32.
// ---------------------------------------------------------------------------
template <int TAPS, int KW, int PAD, bool RESID>
__global__ __launch_bounds__(256) void conv_mfma(
    const __bf16* __restrict__ A,
    const __bf16* __restrict__ Wt,
    const float* __restrict__ gg, const float* __restrict__ bb,
    const float* __restrict__ mm, const float* __restrict__ vv,
    const float* __restrict__ temp,
    void* __restrict__ outp)
{
    const int K  = TAPS * 384;
    const int m0 = blockIdx.x * 128;
    const int n0 = blockIdx.y * 128;
    const int t  = threadIdx.x;
    const int lane  = t & 63, w = t >> 6;
    const int wm    = (w & 1) * 64, wn = (w >> 1) * 64;
    const int col16 = lane & 15,  quad = lane >> 4;

    __shared__ __bf16 As[128 * 32];
    __shared__ __bf16 Bs[128 * 32];

    // staging: chunk c (16B) -> row c>>2, k-group c&3; thread t owns c=t, c=t+256
    const int r0 = t >> 2, kg = t & 3;
    const int mrow0 = m0 + r0, mrow1 = m0 + r0 + 64;
    const int b0 = mrow0 / 144, p0 = mrow0 - b0 * 144;
    const int b1 = mrow1 / 144, p1 = mrow1 - b1 * 144;
    const int y0 = p0 / 12, x0 = p0 - y0 * 12;
    const int y1 = p1 / 12, x1 = p1 - y1 * 12;
    const __bf16* Ab0 = A + (size_t)b0 * 144 * 384 + kg * 8;
    const __bf16* Ab1 = A + (size_t)b1 * 144 * 384 + kg * 8;
    const __bf16* Bp0 = Wt + (size_t)(n0 + r0)      * K + kg * 8;
    const __bf16* Bp1 = Wt + (size_t)(n0 + r0 + 64) * K + kg * 8;

    f32x4 acc[4][4];
#pragma unroll
    for (int mi = 0; mi < 4; ++mi)
#pragma unroll
        for (int ni = 0; ni < 4; ++ni)
            acc[mi][ni] = (f32x4){0.f, 0.f, 0.f, 0.f};

    for (int tap = 0; tap < TAPS; ++tap) {
        const int ky = tap / KW - PAD, kx = tap % KW - PAD;
        const int sy0 = min(max(y0 + ky, 0), 11), sx0 = min(max(x0 + kx, 0), 11);
        const int sy1 = min(max(y1 + ky, 0), 11), sx1 = min(max(x1 + kx, 0), 11);
        const __bf16* aP0 = Ab0 + (size_t)(sy0 * 12 + sx0) * 384;
        const __bf16* aP1 = Ab1 + (size_t)(sy1 * 12 + sx1) * 384;
        const __bf16* bP0 = Bp0 + (size_t)tap * 384;
        const __bf16* bP1 = Bp1 + (size_t)tap * 384;

#pragma unroll
        for (int j = 0; j < 12; ++j) {            // 384 ic / 32 per step
            __syncthreads();                      // prev tile reads complete
            load16(aP0 + j * 32, &As[t * 8]);
            load16(aP1 + j * 32, &As[(t + 256) * 8]);
            load16(bP0 + j * 32, &Bs[t * 8]);
            load16(bP1 + j * 32, &Bs[(t + 256) * 8]);
            __syncthreads();                      // staging complete (vmcnt drain)

            bf16x8 av[4], bv[4];
#pragma unroll
            for (int mi = 0; mi < 4; ++mi)
                av[mi] = *(const bf16x8*)&As[(wm + mi * 16 + col16) * 32 + quad * 8];
#pragma unroll
            for (int ni = 0; ni < 4; ++ni)
                bv[ni] = *(const bf16x8*)&Bs[(wn + ni * 16 + col16) * 32 + quad * 8];
#pragma unroll
            for (int mi = 0; mi < 4; ++mi)
#pragma unroll
                for (int ni = 0; ni < 4; ++ni)
                    acc[mi][ni] = __builtin_amdgcn_mfma_f32_16x16x32_bf16(
                        av[mi], bv[ni], acc[mi][ni], 0, 0, 0);
        }
    }

    // Epilogue: BN + leaky (+ residual).  D: row = quad*4+reg, col = lane&15.
#pragma unroll
    for (int ni = 0; ni < 4; ++ni) {
        const int gn = n0 + wn + ni * 16 + col16;
        const float scale = gg[gn] * rsqrtf(vv[gn] + 1e-5f);
        const float shift = bb[gn] - mm[gn] * scale;
        if (!RESID) {
            __bf16* h1 = (__bf16*)outp;
#pragma unroll
            for (int mi = 0; mi < 4; ++mi) {
                const int gm = m0 + wm + mi * 16 + quad * 4;
#pragma unroll
                for (int r = 0; r < 4; ++r) {
                    float v = acc[mi][ni][r] * scale + shift;
                    v = (v >= 0.f) ? v : 0.01f * v;
                    h1[(size_t)(gm + r) * 384 + gn] = (__bf16)v;
                }
            }
        } else {
            float* outF = (float*)outp;
#pragma unroll
            for (int mi = 0; mi < 4; ++mi) {
                const int gm = m0 + wm + mi * 16 + quad * 4;
#pragma unroll
                for (int r = 0; r < 4; ++r) {
                    float v = acc[mi][ni][r] * scale + shift;
                    v = (v >= 0.f) ? v : 0.01f * v;
                    outF[(size_t)(gm + r) * 384 + gn] =
                        temp[(size_t)(gm + r) * 384 + gn] + v;
                }
            }
        }
    }
}

// ---------------------------------------------------------------------------
extern "C" void kernel_launch(void* const* d_in, const int* in_sizes, int n_in,
                              void* d_out, int out_size, void* d_ws, size_t ws_size,
                              hipStream_t stream) {
    const float* temp   = (const float*)d_in[0];
    const float* target = (const float*)d_in[1];
    const float* bbox   = (const float*)d_in[2];
    const float* W1     = (const float*)d_in[3];
    const float* g1     = (const float*)d_in[4];
    const float* b1     = (const float*)d_in[5];
    const float* m1     = (const float*)d_in[6];
    const float* v1     = (const float*)d_in[7];
    const float* W2     = (const float*)d_in[8];
    const float* g2     = (const float*)d_in[9];
    const float* b2     = (const float*)d_in[10];
    const float* m2     = (const float*)d_in[11];
    const float* v2     = (const float*)d_in[12];
    float* out = (float*)d_out;

    __bf16* ta  = (__bf16*)d_ws;                          // 256*144*384
    __bf16* h1  = ta  + (size_t)NBATCH * 144 * CDIM;      // 256*144*384
    __bf16* Wt1 = h1  + (size_t)NBATCH * 144 * CDIM;      // 384*25*384
    __bf16* Wt2 = Wt1 + (size_t)CDIM * 25 * CDIM;         // 384*9*384

    prep_w<<<dim3((CDIM * CDIM * 25 + 255) / 256), dim3(256), 0, stream>>>(W1, Wt1, 25);
    prep_w<<<dim3((CDIM * CDIM * 9  + 255) / 256), dim3(256), 0, stream>>>(W2, Wt2, 9);
    gather_bf16<<<dim3(NBATCH), dim3(256), 0, stream>>>(target, bbox, ta);

    // M = 256*144 = 36864 = 288*128 ; N = 384 = 3*128
    conv_mfma<25, 5, 2, false><<<dim3(288, 3), dim3(256), 0, stream>>>(
        ta, Wt1, g1, b1, m1, v1, nullptr, (void*)h1);
    conv_mfma<9, 3, 1, true><<<dim3(288, 3), dim3(256), 0, stream>>>(
        h1, Wt2, g2, b2, m2, v2, temp, (void*)out);
}

// Round 3
// 912.555 us; speedup vs baseline: 6.5752x; 1.0814x over previous
//
#include <hip/hip_runtime.h>
#include <math.h>

#define NBATCH 256
#define CDIM   384

typedef __attribute__((ext_vector_type(4))) float  f32x4;
typedef __attribute__((ext_vector_type(8))) __bf16 bf16x8;
typedef __attribute__((ext_vector_type(4))) __bf16 bf16x4;

__device__ __forceinline__ void load16(const void* g, void* l) {
    __builtin_amdgcn_global_load_lds(
        (const __attribute__((address_space(1))) void*)g,
        (__attribute__((address_space(3))) void*)l, 16, 0, 0);
}

// ---------------------------------------------------------------------------
// Gather: target (B,576,384) fp32 -> ta (B,144,384) bf16, pixel-major. float4.
// ---------------------------------------------------------------------------
__global__ __launch_bounds__(256) void gather_bf16(
    const float* __restrict__ target,
    const float* __restrict__ bbox,
    __bf16* __restrict__ ta)
{
    const int b = blockIdx.x, t = threadIdx.x;
    __shared__ int pos[144];

    if (t < 144) {
        const float bx0 = bbox[b * 4 + 0] * 24.f;
        const float by0 = bbox[b * 4 + 1] * 24.f;
        const float bw  = bbox[b * 4 + 2] * 24.f;
        const float bh  = bbox[b * 4 + 3] * 24.f;
        const float l0 = (bw + bh) * 0.5f;
        const float l  = sqrtf((bw + l0) * (bh + l0));
        const int xmin = (int)fminf(fmaxf(ceilf (bx0 - l * 0.5f), 0.f), 23.f);
        const int ymin = (int)fminf(fmaxf(ceilf (by0 - l * 0.5f), 0.f), 23.f);
        const int xmax = (int)fminf(fmaxf(truncf(bx0 + l * 0.5f), 0.f), 23.f);
        const int ymax = (int)fminf(fmaxf(truncf(by0 + l * 0.5f), 0.f), 23.f);
        const int i = t / 12, j = t % 12;
        int r = ymin + (i * (ymax - ymin)) / 12;
        int c = xmin + (j * (xmax - xmin)) / 12;
        r = min(max(r, 0), 23);
        c = min(max(c, 0), 23);
        pos[t] = r * 24 + c;
    }
    __syncthreads();

    const float* tb  = target + (size_t)b * 576 * 384;
    __bf16*      tab = ta     + (size_t)b * 144 * 384;
    for (int idx = t; idx < 144 * 96; idx += 256) {
        const int p = idx / 96, c4 = idx - p * 96;
        const float4 v = *(const float4*)&tb[(size_t)pos[p] * 384 + c4 * 4];
        bf16x4 o = { (__bf16)v.x, (__bf16)v.y, (__bf16)v.z, (__bf16)v.w };
        *(bf16x4*)&tab[(size_t)p * 384 + c4 * 4] = o;
    }
}

// ---------------------------------------------------------------------------
// Weight prep (coalesced both sides): W (oc, ic, taps) fp32 -> Wt (oc, tap, ic)
// bf16, one oc per block, transpose through LDS.
// ---------------------------------------------------------------------------
template <int TAPS>
__global__ __launch_bounds__(256) void prep_w(
    const float* __restrict__ W, __bf16* __restrict__ Wt)
{
    const int K = TAPS * 384;
    __shared__ float ws[TAPS * 384];
    const int oc = blockIdx.x;
    const float* src = W + (size_t)oc * K;
    for (int i = threadIdx.x; i < K; i += 256) ws[i] = src[i];
    __syncthreads();
    __bf16* dst = Wt + (size_t)oc * K;
    for (int i = threadIdx.x; i < K; i += 256) {
        const int tap = i / 384;
        const int ic  = i - tap * 384;
        dst[i] = (__bf16)ws[ic * TAPS + tap];
    }
}

// ---------------------------------------------------------------------------
// Implicit-GEMM conv (tap-decomposed) + BN + leaky (+ residual).
// A: (B*144, 384) bf16 pixel-major.  Wt: (384, TAPS*384) bf16.
// BM=BN=128, BK=32, 4 waves (64x64 each, 4x4 mfma 16x16x32).
// Single-barrier double-buffered pipeline + XOR-swizzled LDS (conflict-free).
// ---------------------------------------------------------------------------
template <int TAPS, int KW, int PAD, bool RESID>
__global__ __launch_bounds__(256, 3) void conv_mfma(
    const __bf16* __restrict__ A,
    const __bf16* __restrict__ Wt,
    const float* __restrict__ gg, const float* __restrict__ bb,
    const float* __restrict__ mm, const float* __restrict__ vv,
    const float* __restrict__ temp,
    void* __restrict__ outp)
{
    const int K  = TAPS * 384;
    const int IT = TAPS * 12;          // K-iterations of 32
    const int m0 = blockIdx.x * 128;
    const int n0 = blockIdx.y * 128;
    const int t  = threadIdx.x;
    const int lane  = t & 63, w = t >> 6;
    const int wm    = (w & 1) * 64, wn = (w >> 1) * 64;
    const int col16 = lane & 15,  quad = lane >> 4;

    __shared__ __bf16 As0[128 * 32], As1[128 * 32];
    __shared__ __bf16 Bs0[128 * 32], Bs1[128 * 32];

    // staging: thread t owns 16B slot t (rows r0, r0+64); swizzled k-group
    const int r0   = t >> 2, slot = t & 3;
    const int kg   = slot ^ ((r0 >> 1) & 3);
    const int mrow0 = m0 + r0, mrow1 = m0 + r0 + 64;
    const int b0 = mrow0 / 144, p0 = mrow0 - b0 * 144;
    const int b1 = mrow1 / 144, p1 = mrow1 - b1 * 144;
    const int y0 = p0 / 12, x0 = p0 - y0 * 12;
    const int y1 = p1 / 12, x1 = p1 - y1 * 12;
    const __bf16* Ab0 = A + (size_t)b0 * 144 * 384 + kg * 8;
    const __bf16* Ab1 = A + (size_t)b1 * 144 * 384 + kg * 8;

    // loop-invariant swizzled LDS read offsets (elements)
    int offA[4], offB[4];
#pragma unroll
    for (int mi = 0; mi < 4; ++mi) {
        const int r = wm + mi * 16 + col16;
        offA[mi] = r * 32 + (quad ^ ((r >> 1) & 3)) * 8;
    }
#pragma unroll
    for (int ni = 0; ni < 4; ++ni) {
        const int r = wn + ni * 16 + col16;
        offB[ni] = r * 32 + (quad ^ ((r >> 1) & 3)) * 8;
    }

    f32x4 acc[4][4];
#pragma unroll
    for (int mi = 0; mi < 4; ++mi)
#pragma unroll
        for (int ni = 0; ni < 4; ++ni)
            acc[mi][ni] = (f32x4){0.f, 0.f, 0.f, 0.f};

    // next-tile bookkeeping (tile index = tapn*12 + jn)
    int jn = 0, tapn = 0;
    const __bf16* aT0;
    const __bf16* aT1;
    {   // tap 0 bases
        const int sy0 = min(max(y0 - PAD, 0), 11), sx0 = min(max(x0 - PAD, 0), 11);
        const int sy1 = min(max(y1 - PAD, 0), 11), sx1 = min(max(x1 - PAD, 0), 11);
        aT0 = Ab0 + (size_t)(sy0 * 12 + sx0) * 384;
        aT1 = Ab1 + (size_t)(sy1 * 12 + sx1) * 384;
    }
    const __bf16* bT0 = Wt + (size_t)(n0 + r0)      * K + kg * 8;
    const __bf16* bT1 = Wt + (size_t)(n0 + r0 + 64) * K + kg * 8;

    auto issue = [&](__bf16* SA, __bf16* SB) {
        load16(aT0 + jn * 32, &SA[t * 8]);
        load16(aT1 + jn * 32, &SA[(t + 256) * 8]);
        load16(bT0 + jn * 32, &SB[t * 8]);
        load16(bT1 + jn * 32, &SB[(t + 256) * 8]);
    };
    auto advance = [&]() {
        if (++jn == 12) {
            jn = 0;
            ++tapn;
            if (tapn < TAPS) {
                const int ky = tapn / KW - PAD, kx = tapn % KW - PAD;
                const int sy0 = min(max(y0 + ky, 0), 11), sx0 = min(max(x0 + kx, 0), 11);
                const int sy1 = min(max(y1 + ky, 0), 11), sx1 = min(max(x1 + kx, 0), 11);
                aT0 = Ab0 + (size_t)(sy0 * 12 + sx0) * 384;
                aT1 = Ab1 + (size_t)(sy1 * 12 + sx1) * 384;
                bT0 += 384;
                bT1 += 384;
            }
        }
    };
    auto mfma_step = [&](const __bf16* SA, const __bf16* SB, bool do_issue,
                         __bf16* NA, __bf16* NB_) {
        __syncthreads();                       // tile resident; other buf free
        bf16x8 av[4], bv[4];
#pragma unroll
        for (int mi = 0; mi < 4; ++mi) av[mi] = *(const bf16x8*)&SA[offA[mi]];
#pragma unroll
        for (int ni = 0; ni < 4; ++ni) bv[ni] = *(const bf16x8*)&SB[offB[ni]];
        if (do_issue) issue(NA, NB_);          // latency overlaps MFMA below
#pragma unroll
        for (int mi = 0; mi < 4; ++mi)
#pragma unroll
            for (int ni = 0; ni < 4; ++ni)
                acc[mi][ni] = __builtin_amdgcn_mfma_f32_16x16x32_bf16(
                    av[mi], bv[ni], acc[mi][ni], 0, 0, 0);
    };

    issue(As0, Bs0);                           // prologue: tile 0 -> buf0

    for (int it2 = 0; it2 < IT; it2 += 2) {
        advance();                             // -> tile it2+1
        mfma_step(As0, Bs0, true, As1, Bs1);
        advance();                             // -> tile it2+2
        mfma_step(As1, Bs1, it2 + 2 < IT, As0, Bs0);
    }

    // Epilogue: BN + leaky (+ residual).  D: row = quad*4+reg, col = lane&15.
#pragma unroll
    for (int ni = 0; ni < 4; ++ni) {
        const int gn = n0 + wn + ni * 16 + col16;
        const float scale = gg[gn] * rsqrtf(vv[gn] + 1e-5f);
        const float shift = bb[gn] - mm[gn] * scale;
        if (!RESID) {
            __bf16* h1 = (__bf16*)outp;
#pragma unroll
            for (int mi = 0; mi < 4; ++mi) {
                const int gm = m0 + wm + mi * 16 + quad * 4;
#pragma unroll
                for (int r = 0; r < 4; ++r) {
                    float v = acc[mi][ni][r] * scale + shift;
                    v = (v >= 0.f) ? v : 0.01f * v;
                    h1[(size_t)(gm + r) * 384 + gn] = (__bf16)v;
                }
            }
        } else {
            float* outF = (float*)outp;
#pragma unroll
            for (int mi = 0; mi < 4; ++mi) {
                const int gm = m0 + wm + mi * 16 + quad * 4;
#pragma unroll
                for (int r = 0; r < 4; ++r) {
                    float v = acc[mi][ni][r] * scale + shift;
                    v = (v >= 0.f) ? v : 0.01f * v;
                    outF[(size_t)(gm + r) * 384 + gn] =
                        temp[(size_t)(gm + r) * 384 + gn] + v;
                }
            }
        }
    }
}

// ---------------------------------------------------------------------------
extern "C" void kernel_launch(void* const* d_in, const int* in_sizes, int n_in,
                              void* d_out, int out_size, void* d_ws, size_t ws_size,
                              hipStream_t stream) {
    const float* temp   = (const float*)d_in[0];
    const float* target = (const float*)d_in[1];
    const float* bbox   = (const float*)d_in[2];
    const float* W1     = (const float*)d_in[3];
    const float* g1     = (const float*)d_in[4];
    const float* b1     = (const float*)d_in[5];
    const float* m1     = (const float*)d_in[6];
    const float* v1     = (const float*)d_in[7];
    const float* W2     = (const float*)d_in[8];
    const float* g2     = (const float*)d_in[9];
    const float* b2     = (const float*)d_in[10];
    const float* m2     = (const float*)d_in[11];
    const float* v2     = (const float*)d_in[12];
    float* out = (float*)d_out;

    __bf16* ta  = (__bf16*)d_ws;                          // 256*144*384
    __bf16* h1  = ta  + (size_t)NBATCH * 144 * CDIM;      // 256*144*384
    __bf16* Wt1 = h1  + (size_t)NBATCH * 144 * CDIM;      // 384*25*384
    __bf16* Wt2 = Wt1 + (size_t)CDIM * 25 * CDIM;         // 384*9*384

    prep_w<25><<<dim3(CDIM), dim3(256), 0, stream>>>(W1, Wt1);
    prep_w<9><<<dim3(CDIM), dim3(256), 0, stream>>>(W2, Wt2);
    gather_bf16<<<dim3(NBATCH), dim3(256), 0, stream>>>(target, bbox, ta);

    // M = 256*144 = 36864 = 288*128 ; N = 384 = 3*128
    conv_mfma<25, 5, 2, false><<<dim3(288, 3), dim3(256), 0, stream>>>(
        ta, Wt1, g1, b1, m1, v1, nullptr, (void*)h1);
    conv_mfma<9, 3, 1, true><<<dim3(288, 3), dim3(256), 0, stream>>>(
        h1, Wt2, g2, b2, m2, v2, temp, (void*)out);
}